// Round 1
// baseline (219.337 us; speedup 1.0000x reference)
//
#include <hip/hip_runtime.h>

// TriMipEncoding: N pts, 3 planes (512^2, 16 ch), 8 mip levels, trilinear sample.
// Layout: level 0 stays in fm (d_in[2]); levels 1..7 packed per-plane in d_ws.
//   ws plane p, level l (l>=1): offset (in texels) = (262144 - 4*sz*sz)/3, sz = 512>>l
//   plane stride = 87376 texels (sum of 256^2..4^2)

#define FM_PLANE_STRIDE (262144 * 16)   // floats per plane in fm
#define WS_PLANE_STRIDE (87376 * 16)    // floats per plane in ws pyramid

__device__ __forceinline__ float4 ld4(const float* p) {
    return *reinterpret_cast<const float4*>(p);
}

// 2x2 box downsample: dst size s = 1<<ls, src size 2s. One thread per
// (texel, channel-quad); blockIdx.y = plane.
__global__ __launch_bounds__(256) void mip_build(
    const float* __restrict__ src, float* __restrict__ dst,
    int ls, int srcPlaneStride, int dstPlaneStride)
{
    const int s = 1 << ls;
    int t = blockIdx.x * blockDim.x + threadIdx.x;
    const int perPlane = s * s * 4;
    if (t >= perPlane) return;
    const int p = blockIdx.y;
    const int q = t & 3;
    const int idx = t >> 2;
    const int y = idx >> ls;
    const int x = idx & (s - 1);
    const int ss = s << 1;
    const float* sp = src + (size_t)p * srcPlaneStride
                          + ((size_t)(2 * y) * ss + 2 * x) * 16 + q * 4;
    float4 a = ld4(sp);
    float4 b = ld4(sp + 16);
    float4 c = ld4(sp + (size_t)ss * 16);
    float4 d = ld4(sp + (size_t)ss * 16 + 16);
    float4 r;
    r.x = (a.x + b.x + c.x + d.x) * 0.25f;
    r.y = (a.y + b.y + c.y + d.y) * 0.25f;
    r.z = (a.z + b.z + c.z + d.z) * 0.25f;
    r.w = (a.w + b.w + c.w + d.w) * 0.25f;
    float* dp = dst + (size_t)p * dstPlaneStride + ((size_t)y * s + x) * 16 + q * 4;
    *reinterpret_cast<float4*>(dp) = r;
}

__device__ __forceinline__ float4 bilerp(
    const float* __restrict__ fm, const float* __restrict__ mips,
    int p, int l, float u, float v, int q)
{
    const int sz = 512 >> l;
    const float fsz = (float)sz;
    float px = u * fsz - 0.5f;
    float py = v * fsz - 0.5f;
    float xf = floorf(px);
    float yf = floorf(py);
    float fx = px - xf;
    float fy = py - yf;
    int xi = (int)xf;
    int yi = (int)yf;
    int xa = min(max(xi, 0), sz - 1);
    int xb = min(xi + 1, sz - 1);      // xi+1 >= 0 always (xi >= -1)
    int ya = min(max(yi, 0), sz - 1);
    int yb = min(yi + 1, sz - 1);
    const float* base;
    if (l == 0) {
        base = fm + (size_t)p * FM_PLANE_STRIDE;
    } else {
        unsigned off = (262144u - ((unsigned)(sz * sz) << 2)) / 3u;  // texels
        base = mips + (size_t)p * WS_PLANE_STRIDE + (size_t)off * 16;
    }
    const float* r0 = base + (size_t)(ya * sz) * 16 + q * 4;
    const float* r1 = base + (size_t)(yb * sz) * 16 + q * 4;
    float4 f00 = ld4(r0 + xa * 16);
    float4 f01 = ld4(r0 + xb * 16);
    float4 f10 = ld4(r1 + xa * 16);
    float4 f11 = ld4(r1 + xb * 16);
    float gx = 1.f - fx, gy = 1.f - fy;
    float4 r;
    r.x = (f00.x * gx + f01.x * fx) * gy + (f10.x * gx + f11.x * fx) * fy;
    r.y = (f00.y * gx + f01.y * fx) * gy + (f10.y * gx + f11.y * fx) * fy;
    r.z = (f00.z * gx + f01.z * fx) * gy + (f10.z * gx + f11.z * fx) * fy;
    r.w = (f00.w * gx + f01.w * fx) * gy + (f10.w * gx + f11.w * fx) * fy;
    return r;
}

// One thread per (point n, plane p, channel-quad q): t = (n*3 + p)*4 + q.
// Output float4 index == t (out is (N, 3, 16) row-major) -> coalesced store.
__global__ __launch_bounds__(256) void trimip_sample(
    const float* __restrict__ xyz, const float* __restrict__ level,
    const float* __restrict__ fm, const float* __restrict__ mips,
    float* __restrict__ out, int N)
{
    int t = blockIdx.x * blockDim.x + threadIdx.x;
    if (t >= N * 12) return;
    const int q = t & 3;
    const int r = t >> 2;
    const int n = r / 3;
    const int p = r - n * 3;

    const float c0 = xyz[n * 3 + 0];
    const float c1 = xyz[n * 3 + 1];
    const float c2 = xyz[n * 3 + 2];
    // plane0 -> (y,z); plane1 -> (x,z); plane2 -> (x,y)
    const float u = (p == 0) ? c1 : c0;
    const float v = (p == 2) ? c1 : c2;

    float lv = level[n];
    lv = fminf(fmaxf(lv, 0.f), 7.f);
    float lf = floorf(lv);
    float f = lv - lf;
    int l0 = (int)lf;
    int l1 = min(l0 + 1, 7);

    float4 s0 = bilerp(fm, mips, p, l0, u, v, q);
    float4 s1 = bilerp(fm, mips, p, l1, u, v, q);
    float g = 1.f - f;
    float4 o;
    o.x = s0.x * g + s1.x * f;
    o.y = s0.y * g + s1.y * f;
    o.z = s0.z * g + s1.z * f;
    o.w = s0.w * g + s1.w * f;
    reinterpret_cast<float4*>(out)[t] = o;
}

extern "C" void kernel_launch(void* const* d_in, const int* in_sizes, int n_in,
                              void* d_out, int out_size, void* d_ws, size_t ws_size,
                              hipStream_t stream) {
    const float* xyz   = (const float*)d_in[0];   // (N,3) fp32
    const float* level = (const float*)d_in[1];   // (N,1) fp32
    const float* fm    = (const float*)d_in[2];   // (3,512,512,16) fp32
    float* mips = (float*)d_ws;                   // (3, 87376, 16) fp32 levels 1..7
    float* out  = (float*)d_out;                  // (N, 48) fp32
    const int N = in_sizes[1];                    // level has N elements

    // Build mip levels 1..7 (each depends on the previous).
    unsigned off = 0;                 // texel offset of level l within a ws plane
    const float* src = fm;
    int srcStride = FM_PLANE_STRIDE;
    for (int l = 1; l <= 7; ++l) {
        const int s = 512 >> l;
        const int ls = 9 - l;
        float* dst = mips + (size_t)off * 16;
        const int perPlane = s * s * 4;
        dim3 grid((perPlane + 255) / 256, 3);
        mip_build<<<grid, dim3(256), 0, stream>>>(src, dst, ls, srcStride, WS_PLANE_STRIDE);
        src = dst;
        srcStride = WS_PLANE_STRIDE;
        off += s * s;
    }

    const int total = N * 12;
    const int blocks = (total + 255) / 256;
    trimip_sample<<<blocks, 256, 0, stream>>>(xyz, level, fm, mips, out, N);
}

// Round 2
// 211.250 us; speedup vs baseline: 1.0383x; 1.0383x over previous
//
#include <hip/hip_runtime.h>

// TriMipEncoding: N pts, 3 planes (512^2, 16 ch), 8 mip levels, trilinear sample.
// Layout: level 0 stays in fm (d_in[2]); levels 1..7 packed per-plane in d_ws.
//   ws plane p, level l (l>=1): texel offset = (262144 - 4*sz*sz)/3, sz = 512>>l
//   plane stride = 87376 texels (sum of 256^2..4^2)
// Pyramid built in 2 kernels: mip_build (L0->L1, BW-bound) + mip_tail
// (L2..L7 fused via LDS reduction tree) -- the 7-kernel chain cost ~142us
// of latency for <20us of work (R1 counters).

#define FM_PLANE_STRIDE (262144 * 16)   // floats per plane in fm
#define WS_PLANE_STRIDE (87376 * 16)    // floats per plane in ws pyramid

__device__ __forceinline__ float4 ld4(const float* p) {
    return *reinterpret_cast<const float4*>(p);
}
__device__ __forceinline__ void st4(float* p, float4 v) {
    *reinterpret_cast<float4*>(p) = v;
}
__device__ __forceinline__ float4 avg4(float4 a, float4 b, float4 c, float4 d) {
    float4 r;
    r.x = (a.x + b.x + c.x + d.x) * 0.25f;
    r.y = (a.y + b.y + c.y + d.y) * 0.25f;
    r.z = (a.z + b.z + c.z + d.z) * 0.25f;
    r.w = (a.w + b.w + c.w + d.w) * 0.25f;
    return r;
}

// 2x2 box downsample L0 -> L1. One thread per (texel, channel-quad);
// blockIdx.y = plane.
__global__ __launch_bounds__(256) void mip_build(
    const float* __restrict__ src, float* __restrict__ dst)
{
    const int s = 256;                 // L1 size
    int t = blockIdx.x * blockDim.x + threadIdx.x;
    const int p = blockIdx.y;
    const int q = t & 3;
    const int idx = t >> 2;
    const int y = idx >> 8;
    const int x = idx & 255;
    const int ss = 512;
    const float* sp = src + (size_t)p * FM_PLANE_STRIDE
                          + ((size_t)(2 * y) * ss + 2 * x) * 16 + q * 4;
    float4 a = ld4(sp);
    float4 b = ld4(sp + 16);
    float4 c = ld4(sp + (size_t)ss * 16);
    float4 d = ld4(sp + (size_t)ss * 16 + 16);
    float* dp = dst + (size_t)p * WS_PLANE_STRIDE + ((size_t)y * s + x) * 16 + q * 4;
    st4(dp, avg4(a, b, c, d));
}

// Fused L2..L7 build. Block = (tile of 32x32 L2 texels, channel-quad q, plane p).
// Grid (16, 4, 3). Reduction tree through LDS; every level written to global.
__global__ __launch_bounds__(256) void mip_tail(float* __restrict__ mips)
{
    const int tile = blockIdx.x;       // 0..15
    const int q    = blockIdx.y;       // 0..3
    const int p    = blockIdx.z;       // 0..2
    const int ty = tile >> 2, tx = tile & 3;
    const int tid = threadIdx.x;

    __shared__ float4 A[32 * 32];      // 16 KB
    __shared__ float4 B[16 * 16];      // 4 KB

    float* plane = mips + (size_t)p * WS_PLANE_STRIDE;
    const float* L1 = plane;                         // 256^2 texels
    float* L2 = plane + (size_t)65536 * 16;          // 128^2
    float* L3 = plane + (size_t)81920 * 16;          // 64^2
    float* L4 = plane + (size_t)86016 * 16;          // 32^2
    float* L5 = plane + (size_t)87040 * 16;          // 16^2
    float* L6 = plane + (size_t)87296 * 16;          // 8^2
    float* L7 = plane + (size_t)87360 * 16;          // 4^2

    // L2: 32x32 tile, 4 texels/thread, from L1 global reads.
    #pragma unroll
    for (int k = 0; k < 4; ++k) {
        int li = tid + k * 256;
        int ly = li >> 5, lx = li & 31;
        int gy = ty * 32 + ly, gx = tx * 32 + lx;
        const float* sp = L1 + ((size_t)(2 * gy) * 256 + 2 * gx) * 16 + q * 4;
        float4 r = avg4(ld4(sp), ld4(sp + 16),
                        ld4(sp + 256 * 16), ld4(sp + 256 * 16 + 16));
        A[li] = r;
        st4(L2 + ((size_t)gy * 128 + gx) * 16 + q * 4, r);
    }
    __syncthreads();

    // L3: 16x16 tile (A 32-wide -> B 16-wide)
    if (tid < 256) {
        int ly = tid >> 4, lx = tid & 15;
        float4 r = avg4(A[(2 * ly) * 32 + 2 * lx],     A[(2 * ly) * 32 + 2 * lx + 1],
                        A[(2 * ly + 1) * 32 + 2 * lx], A[(2 * ly + 1) * 32 + 2 * lx + 1]);
        B[tid] = r;
        st4(L3 + ((size_t)(ty * 16 + ly) * 64 + tx * 16 + lx) * 16 + q * 4, r);
    }
    __syncthreads();

    // L4: 8x8 tile (B 16-wide -> A 8-wide)
    if (tid < 64) {
        int ly = tid >> 3, lx = tid & 7;
        float4 r = avg4(B[(2 * ly) * 16 + 2 * lx],     B[(2 * ly) * 16 + 2 * lx + 1],
                        B[(2 * ly + 1) * 16 + 2 * lx], B[(2 * ly + 1) * 16 + 2 * lx + 1]);
        A[tid] = r;
        st4(L4 + ((size_t)(ty * 8 + ly) * 32 + tx * 8 + lx) * 16 + q * 4, r);
    }
    __syncthreads();

    // L5: 4x4 tile (A 8-wide -> B 4-wide)
    if (tid < 16) {
        int ly = tid >> 2, lx = tid & 3;
        float4 r = avg4(A[(2 * ly) * 8 + 2 * lx],     A[(2 * ly) * 8 + 2 * lx + 1],
                        A[(2 * ly + 1) * 8 + 2 * lx], A[(2 * ly + 1) * 8 + 2 * lx + 1]);
        B[tid] = r;
        st4(L5 + ((size_t)(ty * 4 + ly) * 16 + tx * 4 + lx) * 16 + q * 4, r);
    }
    __syncthreads();

    // L6: 2x2 tile (B 4-wide -> A 2-wide)
    if (tid < 4) {
        int ly = tid >> 1, lx = tid & 1;
        float4 r = avg4(B[(2 * ly) * 4 + 2 * lx],     B[(2 * ly) * 4 + 2 * lx + 1],
                        B[(2 * ly + 1) * 4 + 2 * lx], B[(2 * ly + 1) * 4 + 2 * lx + 1]);
        A[tid] = r;
        st4(L6 + ((size_t)(ty * 2 + ly) * 8 + tx * 2 + lx) * 16 + q * 4, r);
    }
    __syncthreads();

    // L7: 1 texel per tile (A 2-wide)
    if (tid == 0) {
        float4 r = avg4(A[0], A[1], A[2], A[3]);
        st4(L7 + ((size_t)ty * 4 + tx) * 16 + q * 4, r);
    }
}

__device__ __forceinline__ float4 bilerp(
    const float* __restrict__ fm, const float* __restrict__ mips,
    int p, int l, float u, float v, int q)
{
    const int sz = 512 >> l;
    const float fsz = (float)sz;
    float px = u * fsz - 0.5f;
    float py = v * fsz - 0.5f;
    float xf = floorf(px);
    float yf = floorf(py);
    float fx = px - xf;
    float fy = py - yf;
    int xi = (int)xf;
    int yi = (int)yf;
    int xa = min(max(xi, 0), sz - 1);
    int xb = min(xi + 1, sz - 1);      // xi+1 >= 0 always (xi >= -1)
    int ya = min(max(yi, 0), sz - 1);
    int yb = min(yi + 1, sz - 1);
    const float* base;
    if (l == 0) {
        base = fm + (size_t)p * FM_PLANE_STRIDE;
    } else {
        unsigned off = (262144u - ((unsigned)(sz * sz) << 2)) / 3u;  // texels
        base = mips + (size_t)p * WS_PLANE_STRIDE + (size_t)off * 16;
    }
    const float* r0 = base + (size_t)(ya * sz) * 16 + q * 4;
    const float* r1 = base + (size_t)(yb * sz) * 16 + q * 4;
    float4 f00 = ld4(r0 + xa * 16);
    float4 f01 = ld4(r0 + xb * 16);
    float4 f10 = ld4(r1 + xa * 16);
    float4 f11 = ld4(r1 + xb * 16);
    float gx = 1.f - fx, gy = 1.f - fy;
    float4 r;
    r.x = (f00.x * gx + f01.x * fx) * gy + (f10.x * gx + f11.x * fx) * fy;
    r.y = (f00.y * gx + f01.y * fx) * gy + (f10.y * gx + f11.y * fx) * fy;
    r.z = (f00.z * gx + f01.z * fx) * gy + (f10.z * gx + f11.z * fx) * fy;
    r.w = (f00.w * gx + f01.w * fx) * gy + (f10.w * gx + f11.w * fx) * fy;
    return r;
}

// One thread per (point n, plane p, channel-quad q): t = (n*3 + p)*4 + q.
// Output float4 index == t (out is (N, 3, 16) row-major) -> coalesced store.
__global__ __launch_bounds__(256) void trimip_sample(
    const float* __restrict__ xyz, const float* __restrict__ level,
    const float* __restrict__ fm, const float* __restrict__ mips,
    float* __restrict__ out, int N)
{
    int t = blockIdx.x * blockDim.x + threadIdx.x;
    if (t >= N * 12) return;
    const int q = t & 3;
    const int r = t >> 2;
    const int n = r / 3;
    const int p = r - n * 3;

    const float c0 = xyz[n * 3 + 0];
    const float c1 = xyz[n * 3 + 1];
    const float c2 = xyz[n * 3 + 2];
    // plane0 -> (y,z); plane1 -> (x,z); plane2 -> (x,y)
    const float u = (p == 0) ? c1 : c0;
    const float v = (p == 2) ? c1 : c2;

    float lv = level[n];
    lv = fminf(fmaxf(lv, 0.f), 7.f);
    float lf = floorf(lv);
    float f = lv - lf;
    int l0 = (int)lf;
    int l1 = min(l0 + 1, 7);

    float4 s0 = bilerp(fm, mips, p, l0, u, v, q);
    float4 s1 = bilerp(fm, mips, p, l1, u, v, q);
    float g = 1.f - f;
    float4 o;
    o.x = s0.x * g + s1.x * f;
    o.y = s0.y * g + s1.y * f;
    o.z = s0.z * g + s1.z * f;
    o.w = s0.w * g + s1.w * f;
    reinterpret_cast<float4*>(out)[t] = o;
}

extern "C" void kernel_launch(void* const* d_in, const int* in_sizes, int n_in,
                              void* d_out, int out_size, void* d_ws, size_t ws_size,
                              hipStream_t stream) {
    const float* xyz   = (const float*)d_in[0];   // (N,3) fp32
    const float* level = (const float*)d_in[1];   // (N,1) fp32
    const float* fm    = (const float*)d_in[2];   // (3,512,512,16) fp32
    float* mips = (float*)d_ws;                   // (3, 87376, 16) fp32 levels 1..7
    float* out  = (float*)d_out;                  // (N, 48) fp32
    const int N = in_sizes[1];                    // level has N elements

    // L0 -> L1 (bandwidth-bound): 256*256*4 threads per plane.
    mip_build<<<dim3(1024, 3), dim3(256), 0, stream>>>(fm, mips);
    // L2..L7 fused.
    mip_tail<<<dim3(16, 4, 3), dim3(256), 0, stream>>>(mips);

    const int total = N * 12;
    const int blocks = (total + 255) / 256;
    trimip_sample<<<blocks, 256, 0, stream>>>(xyz, level, fm, mips, out, N);
}

// Round 3
// 203.559 us; speedup vs baseline: 1.0775x; 1.0378x over previous
//
#include <hip/hip_runtime.h>
#include <hip/hip_fp16.h>

// TriMipEncoding: N pts, 3 planes (512^2, 16 ch), 8 mip levels, trilinear sample.
//
// Fast path (ws_size >= 33.6 MB): full fp16 pyramid (levels 0..7) in d_ws.
//   Texel = 16 halfs = 32 B -> bilinear taps touch 2 cache lines, not 4.
//   Per-plane texel offset of level l: off(l) = (2^20 - (2^20 >> 2l)) / 3.
//   Plane stride = 349520 texels.
// Fallback (small ws): fp32 path from R2 (L0 read from fm, levels 1..7 in ws).

typedef float  f4v   __attribute__((ext_vector_type(4)));
typedef unsigned int u32x2 __attribute__((ext_vector_type(2)));

#define FM_PLANE_STRIDE (262144 * 16)   // floats per plane in fm
#define WS_PLANE_STRIDE (87376 * 16)    // floats per plane, fp32 fallback pyramid
#define PSTRIDE_H (349520 * 16)         // halfs per plane, fp16 full pyramid
#define WS_H_BYTES (3ull * PSTRIDE_H * 2ull)

__device__ __forceinline__ unsigned lvl_off(int l) {   // texel offset of level l
    return (1048576u - (1048576u >> (2 * l))) / 3u;
}

__device__ __forceinline__ f4v ld4(const float* p) {
    return *reinterpret_cast<const f4v*>(p);
}
__device__ __forceinline__ f4v ld4nt(const float* p) {
    return __builtin_nontemporal_load(reinterpret_cast<const f4v*>(p));
}
__device__ __forceinline__ void st4(float* p, f4v v) {
    *reinterpret_cast<f4v*>(p) = v;
}
__device__ __forceinline__ void st4nt(float* p, f4v v) {
    __builtin_nontemporal_store(v, reinterpret_cast<f4v*>(p));
}
__device__ __forceinline__ f4v ldraw_h(const __half* p) {   // 8 halfs as raw f4v
    return *reinterpret_cast<const f4v*>(p);
}
__device__ __forceinline__ u32x2 pack4(f4v v) {             // 4 floats -> 4 halfs
    __half2 lo = __floats2half2_rn(v.x, v.y);
    __half2 hi = __floats2half2_rn(v.z, v.w);
    u32x2 r;
    r.x = *reinterpret_cast<unsigned*>(&lo);
    r.y = *reinterpret_cast<unsigned*>(&hi);
    return r;
}
__device__ __forceinline__ f4v h4f(const __half* p) {       // 4 halfs -> 4 floats
    u32x2 u = *reinterpret_cast<const u32x2*>(p);
    unsigned a0 = u.x, a1 = u.y;
    __half2 lo = *reinterpret_cast<__half2*>(&a0);
    __half2 hi = *reinterpret_cast<__half2*>(&a1);
    float2 flo = __half22float2(lo), fhi = __half22float2(hi);
    f4v r; r.x = flo.x; r.y = flo.y; r.z = fhi.x; r.w = fhi.y;
    return r;
}
__device__ __forceinline__ float2 up2(float rawcomp) {      // 2 packed halfs -> 2 floats
    unsigned u = __float_as_uint(rawcomp);
    __half2 hh = *reinterpret_cast<__half2*>(&u);
    return __half22float2(hh);
}

// ---------------- fp16 path ----------------

// fm (fp32) -> L0' (fp16) + L1 (fp16). Thread per (L1 texel, quad q); grid (1024, 3).
__global__ __launch_bounds__(256) void mip_convert_l1(
    const float* __restrict__ fm, __half* __restrict__ wsh)
{
    int t = blockIdx.x * 256 + threadIdx.x;
    const int p = blockIdx.y;
    const int q = t & 3, idx = t >> 2;
    const int y = idx >> 8, x = idx & 255;
    const float* sp = fm + (size_t)p * FM_PLANE_STRIDE
                         + ((size_t)(2 * y) * 512 + 2 * x) * 16 + q * 4;
    f4v a = ld4nt(sp);
    f4v b = ld4nt(sp + 16);
    f4v c = ld4nt(sp + 512 * 16);
    f4v d = ld4nt(sp + 512 * 16 + 16);
    __half* L0 = wsh + (size_t)p * PSTRIDE_H;
    size_t o00 = ((size_t)(2 * y) * 512 + 2 * x) * 16 + q * 4;
    *reinterpret_cast<u32x2*>(L0 + o00)                = pack4(a);
    *reinterpret_cast<u32x2*>(L0 + o00 + 16)           = pack4(b);
    *reinterpret_cast<u32x2*>(L0 + o00 + 512 * 16)     = pack4(c);
    *reinterpret_cast<u32x2*>(L0 + o00 + 512 * 16 + 16) = pack4(d);
    f4v m = (a + b + c + d) * 0.25f;   // L1 from fp32 source, single rounding
    __half* L1 = wsh + (size_t)p * PSTRIDE_H + (size_t)262144 * 16;
    *reinterpret_cast<u32x2*>(L1 + ((size_t)y * 256 + x) * 16 + q * 4) = pack4(m);
}

// Fused L2..L7 (fp16). Block = (32x32 L2 tile, quad q, plane p); grid (16,4,3).
__global__ __launch_bounds__(256) void mip_tail_h(__half* __restrict__ wsh)
{
    const int tile = blockIdx.x;
    const int q    = blockIdx.y;
    const int p    = blockIdx.z;
    const int ty = tile >> 2, tx = tile & 3;
    const int tid = threadIdx.x;

    __shared__ f4v A[32 * 32];
    __shared__ f4v B[16 * 16];

    __half* plane = wsh + (size_t)p * PSTRIDE_H;
    const __half* L1 = plane + (size_t)lvl_off(1) * 16;
    __half* L2 = plane + (size_t)lvl_off(2) * 16;
    __half* L3 = plane + (size_t)lvl_off(3) * 16;
    __half* L4 = plane + (size_t)lvl_off(4) * 16;
    __half* L5 = plane + (size_t)lvl_off(5) * 16;
    __half* L6 = plane + (size_t)lvl_off(6) * 16;
    __half* L7 = plane + (size_t)lvl_off(7) * 16;

    #pragma unroll
    for (int k = 0; k < 4; ++k) {
        int li = tid + k * 256;
        int ly = li >> 5, lx = li & 31;
        int gy = ty * 32 + ly, gx = tx * 32 + lx;
        const __half* sp = L1 + ((size_t)(2 * gy) * 256 + 2 * gx) * 16 + q * 4;
        f4v r = (h4f(sp) + h4f(sp + 16) + h4f(sp + 256 * 16) + h4f(sp + 256 * 16 + 16)) * 0.25f;
        A[li] = r;
        *reinterpret_cast<u32x2*>(L2 + ((size_t)gy * 128 + gx) * 16 + q * 4) = pack4(r);
    }
    __syncthreads();

    {   // L3: 16x16
        int ly = tid >> 4, lx = tid & 15;
        f4v r = (A[(2 * ly) * 32 + 2 * lx]     + A[(2 * ly) * 32 + 2 * lx + 1] +
                 A[(2 * ly + 1) * 32 + 2 * lx] + A[(2 * ly + 1) * 32 + 2 * lx + 1]) * 0.25f;
        B[tid] = r;
        *reinterpret_cast<u32x2*>(L3 + ((size_t)(ty * 16 + ly) * 64 + tx * 16 + lx) * 16 + q * 4) = pack4(r);
    }
    __syncthreads();

    if (tid < 64) {   // L4: 8x8
        int ly = tid >> 3, lx = tid & 7;
        f4v r = (B[(2 * ly) * 16 + 2 * lx]     + B[(2 * ly) * 16 + 2 * lx + 1] +
                 B[(2 * ly + 1) * 16 + 2 * lx] + B[(2 * ly + 1) * 16 + 2 * lx + 1]) * 0.25f;
        A[tid] = r;
        *reinterpret_cast<u32x2*>(L4 + ((size_t)(ty * 8 + ly) * 32 + tx * 8 + lx) * 16 + q * 4) = pack4(r);
    }
    __syncthreads();

    if (tid < 16) {   // L5: 4x4
        int ly = tid >> 2, lx = tid & 3;
        f4v r = (A[(2 * ly) * 8 + 2 * lx]     + A[(2 * ly) * 8 + 2 * lx + 1] +
                 A[(2 * ly + 1) * 8 + 2 * lx] + A[(2 * ly + 1) * 8 + 2 * lx + 1]) * 0.25f;
        B[tid] = r;
        *reinterpret_cast<u32x2*>(L5 + ((size_t)(ty * 4 + ly) * 16 + tx * 4 + lx) * 16 + q * 4) = pack4(r);
    }
    __syncthreads();

    if (tid < 4) {    // L6: 2x2
        int ly = tid >> 1, lx = tid & 1;
        f4v r = (B[(2 * ly) * 4 + 2 * lx]     + B[(2 * ly) * 4 + 2 * lx + 1] +
                 B[(2 * ly + 1) * 4 + 2 * lx] + B[(2 * ly + 1) * 4 + 2 * lx + 1]) * 0.25f;
        A[tid] = r;
        *reinterpret_cast<u32x2*>(L6 + ((size_t)(ty * 2 + ly) * 8 + tx * 2 + lx) * 16 + q * 4) = pack4(r);
    }
    __syncthreads();

    if (tid == 0) {   // L7: 1 texel
        f4v r = (A[0] + A[1] + A[2] + A[3]) * 0.25f;
        *reinterpret_cast<u32x2*>(L7 + ((size_t)ty * 4 + tx) * 16 + q * 4) = pack4(r);
    }
}

// Weighted 8-channel bilinear tap from the fp16 pyramid.
__device__ __forceinline__ void bilerp8(
    const __half* __restrict__ wsh, int p, int l, float u, float v, int h, float* o)
{
    const int sz = 512 >> l;
    const float fsz = (float)sz;
    float px = u * fsz - 0.5f;
    float py = v * fsz - 0.5f;
    float xf = floorf(px), yf = floorf(py);
    float fx = px - xf, fy = py - yf;
    int xi = (int)xf, yi = (int)yf;
    int xa = min(max(xi, 0), sz - 1);
    int xb = min(xi + 1, sz - 1);      // xi >= -1 always
    int ya = min(max(yi, 0), sz - 1);
    int yb = min(yi + 1, sz - 1);
    const __half* base = wsh + (size_t)p * PSTRIDE_H + (size_t)lvl_off(l) * 16 + h * 8;
    const __half* r0 = base + (size_t)(ya * sz) * 16;
    const __half* r1 = base + (size_t)(yb * sz) * 16;
    f4v q00 = ldraw_h(r0 + (size_t)xa * 16);
    f4v q01 = ldraw_h(r0 + (size_t)xb * 16);
    f4v q10 = ldraw_h(r1 + (size_t)xa * 16);
    f4v q11 = ldraw_h(r1 + (size_t)xb * 16);
    float gx = 1.f - fx, gy = 1.f - fy;
    float w00 = gx * gy, w01 = fx * gy, w10 = gx * fy, w11 = fx * fy;
    #pragma unroll
    for (int i = 0; i < 4; ++i) {
        float2 a = up2(q00[i]), b = up2(q01[i]), c = up2(q10[i]), d = up2(q11[i]);
        o[2 * i]     = a.x * w00 + b.x * w01 + c.x * w10 + d.x * w11;
        o[2 * i + 1] = a.y * w00 + b.y * w01 + c.y * w10 + d.y * w11;
    }
}

// One thread per (point n, plane p, half h): t = (n*3 + p)*2 + h.
// Thread writes out float4s t*2 and t*2+1 -> contiguous 32 B, coalesced.
__global__ __launch_bounds__(256) void trimip_sample_h(
    const float* __restrict__ xyz, const float* __restrict__ level,
    const __half* __restrict__ wsh, float* __restrict__ out, int N)
{
    int t = blockIdx.x * blockDim.x + threadIdx.x;
    if (t >= N * 6) return;
    const int h = t & 1;
    const int r = t >> 1;
    const int n = r / 3;
    const int p = r - n * 3;

    const float c0 = xyz[n * 3 + 0];
    const float c1 = xyz[n * 3 + 1];
    const float c2 = xyz[n * 3 + 2];
    const float u = (p == 0) ? c1 : c0;
    const float v = (p == 2) ? c1 : c2;

    float lv = level[n];
    lv = fminf(fmaxf(lv, 0.f), 7.f);
    float lf = floorf(lv);
    float f = lv - lf;
    int l0 = (int)lf;
    int l1 = min(l0 + 1, 7);

    float s0[8], s1[8];
    bilerp8(wsh, p, l0, u, v, h, s0);
    bilerp8(wsh, p, l1, u, v, h, s1);
    float g = 1.f - f;
    f4v oa, ob;
    #pragma unroll
    for (int i = 0; i < 4; ++i) {
        oa[i] = s0[i] * g + s1[i] * f;
        ob[i] = s0[4 + i] * g + s1[4 + i] * f;
    }
    st4nt(out + (size_t)t * 8, oa);
    st4nt(out + (size_t)t * 8 + 4, ob);
}

// ---------------- fp32 fallback path (R2 kernels) ----------------

__device__ __forceinline__ f4v avg4(f4v a, f4v b, f4v c, f4v d) {
    return (a + b + c + d) * 0.25f;
}

__global__ __launch_bounds__(256) void mip_build_f(
    const float* __restrict__ src, float* __restrict__ dst)
{
    int t = blockIdx.x * blockDim.x + threadIdx.x;
    const int p = blockIdx.y;
    const int q = t & 3, idx = t >> 2;
    const int y = idx >> 8, x = idx & 255;
    const float* sp = src + (size_t)p * FM_PLANE_STRIDE
                          + ((size_t)(2 * y) * 512 + 2 * x) * 16 + q * 4;
    f4v r = avg4(ld4(sp), ld4(sp + 16), ld4(sp + 512 * 16), ld4(sp + 512 * 16 + 16));
    st4(dst + (size_t)p * WS_PLANE_STRIDE + ((size_t)y * 256 + x) * 16 + q * 4, r);
}

__global__ __launch_bounds__(256) void mip_tail_f(float* __restrict__ mips)
{
    const int tile = blockIdx.x, q = blockIdx.y, p = blockIdx.z;
    const int ty = tile >> 2, tx = tile & 3;
    const int tid = threadIdx.x;
    __shared__ f4v A[32 * 32];
    __shared__ f4v B[16 * 16];
    float* plane = mips + (size_t)p * WS_PLANE_STRIDE;
    const float* L1 = plane;
    float* L2 = plane + (size_t)65536 * 16;
    float* L3 = plane + (size_t)81920 * 16;
    float* L4 = plane + (size_t)86016 * 16;
    float* L5 = plane + (size_t)87040 * 16;
    float* L6 = plane + (size_t)87296 * 16;
    float* L7 = plane + (size_t)87360 * 16;

    #pragma unroll
    for (int k = 0; k < 4; ++k) {
        int li = tid + k * 256;
        int ly = li >> 5, lx = li & 31;
        int gy = ty * 32 + ly, gx = tx * 32 + lx;
        const float* sp = L1 + ((size_t)(2 * gy) * 256 + 2 * gx) * 16 + q * 4;
        f4v r = avg4(ld4(sp), ld4(sp + 16), ld4(sp + 256 * 16), ld4(sp + 256 * 16 + 16));
        A[li] = r;
        st4(L2 + ((size_t)gy * 128 + gx) * 16 + q * 4, r);
    }
    __syncthreads();
    {
        int ly = tid >> 4, lx = tid & 15;
        f4v r = avg4(A[(2 * ly) * 32 + 2 * lx],     A[(2 * ly) * 32 + 2 * lx + 1],
                     A[(2 * ly + 1) * 32 + 2 * lx], A[(2 * ly + 1) * 32 + 2 * lx + 1]);
        B[tid] = r;
        st4(L3 + ((size_t)(ty * 16 + ly) * 64 + tx * 16 + lx) * 16 + q * 4, r);
    }
    __syncthreads();
    if (tid < 64) {
        int ly = tid >> 3, lx = tid & 7;
        f4v r = avg4(B[(2 * ly) * 16 + 2 * lx],     B[(2 * ly) * 16 + 2 * lx + 1],
                     B[(2 * ly + 1) * 16 + 2 * lx], B[(2 * ly + 1) * 16 + 2 * lx + 1]);
        A[tid] = r;
        st4(L4 + ((size_t)(ty * 8 + ly) * 32 + tx * 8 + lx) * 16 + q * 4, r);
    }
    __syncthreads();
    if (tid < 16) {
        int ly = tid >> 2, lx = tid & 3;
        f4v r = avg4(A[(2 * ly) * 8 + 2 * lx],     A[(2 * ly) * 8 + 2 * lx + 1],
                     A[(2 * ly + 1) * 8 + 2 * lx], A[(2 * ly + 1) * 8 + 2 * lx + 1]);
        B[tid] = r;
        st4(L5 + ((size_t)(ty * 4 + ly) * 16 + tx * 4 + lx) * 16 + q * 4, r);
    }
    __syncthreads();
    if (tid < 4) {
        int ly = tid >> 1, lx = tid & 1;
        f4v r = avg4(B[(2 * ly) * 4 + 2 * lx],     B[(2 * ly) * 4 + 2 * lx + 1],
                     B[(2 * ly + 1) * 4 + 2 * lx], B[(2 * ly + 1) * 4 + 2 * lx + 1]);
        A[tid] = r;
        st4(L6 + ((size_t)(ty * 2 + ly) * 8 + tx * 2 + lx) * 16 + q * 4, r);
    }
    __syncthreads();
    if (tid == 0) {
        f4v r = avg4(A[0], A[1], A[2], A[3]);
        st4(L7 + ((size_t)ty * 4 + tx) * 16 + q * 4, r);
    }
}

__device__ __forceinline__ f4v bilerp_f(
    const float* __restrict__ fm, const float* __restrict__ mips,
    int p, int l, float u, float v, int q)
{
    const int sz = 512 >> l;
    const float fsz = (float)sz;
    float px = u * fsz - 0.5f;
    float py = v * fsz - 0.5f;
    float xf = floorf(px), yf = floorf(py);
    float fx = px - xf, fy = py - yf;
    int xi = (int)xf, yi = (int)yf;
    int xa = min(max(xi, 0), sz - 1);
    int xb = min(xi + 1, sz - 1);
    int ya = min(max(yi, 0), sz - 1);
    int yb = min(yi + 1, sz - 1);
    const float* base;
    if (l == 0) {
        base = fm + (size_t)p * FM_PLANE_STRIDE;
    } else {
        unsigned off = (262144u - ((unsigned)(sz * sz) << 2)) / 3u;
        base = mips + (size_t)p * WS_PLANE_STRIDE + (size_t)off * 16;
    }
    const float* r0 = base + (size_t)(ya * sz) * 16 + q * 4;
    const float* r1 = base + (size_t)(yb * sz) * 16 + q * 4;
    f4v f00 = ld4(r0 + xa * 16);
    f4v f01 = ld4(r0 + xb * 16);
    f4v f10 = ld4(r1 + xa * 16);
    f4v f11 = ld4(r1 + xb * 16);
    float gx = 1.f - fx, gy = 1.f - fy;
    return (f00 * gx + f01 * fx) * gy + (f10 * gx + f11 * fx) * fy;
}

__global__ __launch_bounds__(256) void trimip_sample_f(
    const float* __restrict__ xyz, const float* __restrict__ level,
    const float* __restrict__ fm, const float* __restrict__ mips,
    float* __restrict__ out, int N)
{
    int t = blockIdx.x * blockDim.x + threadIdx.x;
    if (t >= N * 12) return;
    const int q = t & 3;
    const int r = t >> 2;
    const int n = r / 3;
    const int p = r - n * 3;
    const float c0 = xyz[n * 3 + 0];
    const float c1 = xyz[n * 3 + 1];
    const float c2 = xyz[n * 3 + 2];
    const float u = (p == 0) ? c1 : c0;
    const float v = (p == 2) ? c1 : c2;
    float lv = level[n];
    lv = fminf(fmaxf(lv, 0.f), 7.f);
    float lf = floorf(lv);
    float f = lv - lf;
    int l0 = (int)lf;
    int l1 = min(l0 + 1, 7);
    f4v s0 = bilerp_f(fm, mips, p, l0, u, v, q);
    f4v s1 = bilerp_f(fm, mips, p, l1, u, v, q);
    f4v o = s0 * (1.f - f) + s1 * f;
    st4nt(out + (size_t)t * 4, o);
}

extern "C" void kernel_launch(void* const* d_in, const int* in_sizes, int n_in,
                              void* d_out, int out_size, void* d_ws, size_t ws_size,
                              hipStream_t stream) {
    const float* xyz   = (const float*)d_in[0];
    const float* level = (const float*)d_in[1];
    const float* fm    = (const float*)d_in[2];
    float* out = (float*)d_out;
    const int N = in_sizes[1];

    if (ws_size >= WS_H_BYTES) {
        __half* wsh = (__half*)d_ws;
        mip_convert_l1<<<dim3(1024, 3), dim3(256), 0, stream>>>(fm, wsh);
        mip_tail_h<<<dim3(16, 4, 3), dim3(256), 0, stream>>>(wsh);
        const int total = N * 6;
        trimip_sample_h<<<(total + 255) / 256, 256, 0, stream>>>(xyz, level, wsh, out, N);
    } else {
        float* mips = (float*)d_ws;
        mip_build_f<<<dim3(1024, 3), dim3(256), 0, stream>>>(fm, mips);
        mip_tail_f<<<dim3(16, 4, 3), dim3(256), 0, stream>>>(mips);
        const int total = N * 12;
        trimip_sample_f<<<(total + 255) / 256, 256, 0, stream>>>(xyz, level, fm, mips, out, N);
    }
}

// Round 4
// 201.244 us; speedup vs baseline: 1.0899x; 1.0115x over previous
//
#include <hip/hip_runtime.h>
#include <hip/hip_fp16.h>

// TriMipEncoding: N pts, 3 planes (512^2, 16 ch), 8 mip levels, trilinear sample.
//
// Fast path (ws_size >= 33.6 MB): full fp16 pyramid (levels 0..7) in d_ws.
//   Texel = 16 halfs = 32 B. Per-plane texel offset of level l:
//   off(l) = (2^20 - (2^20 >> 2l)) / 3. Plane stride = 349520 texels.
// R3 evidence: sampler duration identical at FETCH=0 vs FETCH=122MB -> NOT
// HBM-bound; bound is divergent-gather request rate on the vmem pipe.
// R4: stage levels 5..7 (31.5 KB, all planes) in LDS -> ~36% of tap
// requests move to the (idle) LDS pipe. Block=512: 4 blocks/CU * 31.5 KB
// = 126 KB LDS, full 2048-thread occupancy.

typedef float        f4v   __attribute__((ext_vector_type(4)));
typedef unsigned int u32x2 __attribute__((ext_vector_type(2)));
typedef unsigned int u32x4 __attribute__((ext_vector_type(4)));

#define FM_PLANE_STRIDE (262144 * 16)   // floats per plane in fm
#define WS_PLANE_STRIDE (87376 * 16)    // floats per plane, fp32 fallback pyramid
#define PSTRIDE_H (349520 * 16)         // halfs per plane, fp16 full pyramid
#define WS_H_BYTES (3ull * PSTRIDE_H * 2ull)
#define LVL5_OFF 349184u                // texel offset of level 5 (levels 5..7 contiguous)

__device__ __forceinline__ unsigned lvl_off(int l) {   // texel offset of level l
    return (1048576u - (1048576u >> (2 * l))) / 3u;
}

__device__ __forceinline__ f4v ld4(const float* p) {
    return *reinterpret_cast<const f4v*>(p);
}
__device__ __forceinline__ f4v ld4nt(const float* p) {
    return __builtin_nontemporal_load(reinterpret_cast<const f4v*>(p));
}
__device__ __forceinline__ void st4(float* p, f4v v) {
    *reinterpret_cast<f4v*>(p) = v;
}
__device__ __forceinline__ void st4nt(float* p, f4v v) {
    __builtin_nontemporal_store(v, reinterpret_cast<f4v*>(p));
}
__device__ __forceinline__ f4v ldraw_h(const __half* p) {   // 8 halfs as raw f4v
    return *reinterpret_cast<const f4v*>(p);
}
__device__ __forceinline__ u32x2 pack4(f4v v) {             // 4 floats -> 4 halfs
    __half2 lo = __floats2half2_rn(v.x, v.y);
    __half2 hi = __floats2half2_rn(v.z, v.w);
    u32x2 r;
    r.x = *reinterpret_cast<unsigned*>(&lo);
    r.y = *reinterpret_cast<unsigned*>(&hi);
    return r;
}
__device__ __forceinline__ f4v h4f(const __half* p) {       // 4 halfs -> 4 floats
    u32x2 u = *reinterpret_cast<const u32x2*>(p);
    unsigned a0 = u.x, a1 = u.y;
    __half2 lo = *reinterpret_cast<__half2*>(&a0);
    __half2 hi = *reinterpret_cast<__half2*>(&a1);
    float2 flo = __half22float2(lo), fhi = __half22float2(hi);
    f4v r; r.x = flo.x; r.y = flo.y; r.z = fhi.x; r.w = fhi.y;
    return r;
}
__device__ __forceinline__ float2 up2(float rawcomp) {      // 2 packed halfs -> 2 floats
    unsigned u = __float_as_uint(rawcomp);
    __half2 hh = *reinterpret_cast<__half2*>(&u);
    return __half22float2(hh);
}

// ---------------- fp16 path ----------------

// fm (fp32) -> L0' (fp16) + L1 (fp16). Thread per (L1 texel, quad q); grid (1024, 3).
__global__ __launch_bounds__(256) void mip_convert_l1(
    const float* __restrict__ fm, __half* __restrict__ wsh)
{
    int t = blockIdx.x * 256 + threadIdx.x;
    const int p = blockIdx.y;
    const int q = t & 3, idx = t >> 2;
    const int y = idx >> 8, x = idx & 255;
    const float* sp = fm + (size_t)p * FM_PLANE_STRIDE
                         + ((size_t)(2 * y) * 512 + 2 * x) * 16 + q * 4;
    f4v a = ld4nt(sp);
    f4v b = ld4nt(sp + 16);
    f4v c = ld4nt(sp + 512 * 16);
    f4v d = ld4nt(sp + 512 * 16 + 16);
    __half* L0 = wsh + (size_t)p * PSTRIDE_H;
    size_t o00 = ((size_t)(2 * y) * 512 + 2 * x) * 16 + q * 4;
    *reinterpret_cast<u32x2*>(L0 + o00)                 = pack4(a);
    *reinterpret_cast<u32x2*>(L0 + o00 + 16)            = pack4(b);
    *reinterpret_cast<u32x2*>(L0 + o00 + 512 * 16)      = pack4(c);
    *reinterpret_cast<u32x2*>(L0 + o00 + 512 * 16 + 16) = pack4(d);
    f4v m = (a + b + c + d) * 0.25f;   // L1 from fp32 source, single rounding
    __half* L1 = wsh + (size_t)p * PSTRIDE_H + (size_t)262144 * 16;
    *reinterpret_cast<u32x2*>(L1 + ((size_t)y * 256 + x) * 16 + q * 4) = pack4(m);
}

// Fused L2..L7 (fp16). Block = (32x32 L2 tile, quad q, plane p); grid (16,4,3).
__global__ __launch_bounds__(256) void mip_tail_h(__half* __restrict__ wsh)
{
    const int tile = blockIdx.x;
    const int q    = blockIdx.y;
    const int p    = blockIdx.z;
    const int ty = tile >> 2, tx = tile & 3;
    const int tid = threadIdx.x;

    __shared__ f4v A[32 * 32];
    __shared__ f4v B[16 * 16];

    __half* plane = wsh + (size_t)p * PSTRIDE_H;
    const __half* L1 = plane + (size_t)lvl_off(1) * 16;
    __half* L2 = plane + (size_t)lvl_off(2) * 16;
    __half* L3 = plane + (size_t)lvl_off(3) * 16;
    __half* L4 = plane + (size_t)lvl_off(4) * 16;
    __half* L5 = plane + (size_t)lvl_off(5) * 16;
    __half* L6 = plane + (size_t)lvl_off(6) * 16;
    __half* L7 = plane + (size_t)lvl_off(7) * 16;

    #pragma unroll
    for (int k = 0; k < 4; ++k) {
        int li = tid + k * 256;
        int ly = li >> 5, lx = li & 31;
        int gy = ty * 32 + ly, gx = tx * 32 + lx;
        const __half* sp = L1 + ((size_t)(2 * gy) * 256 + 2 * gx) * 16 + q * 4;
        f4v r = (h4f(sp) + h4f(sp + 16) + h4f(sp + 256 * 16) + h4f(sp + 256 * 16 + 16)) * 0.25f;
        A[li] = r;
        *reinterpret_cast<u32x2*>(L2 + ((size_t)gy * 128 + gx) * 16 + q * 4) = pack4(r);
    }
    __syncthreads();

    {   // L3: 16x16
        int ly = tid >> 4, lx = tid & 15;
        f4v r = (A[(2 * ly) * 32 + 2 * lx]     + A[(2 * ly) * 32 + 2 * lx + 1] +
                 A[(2 * ly + 1) * 32 + 2 * lx] + A[(2 * ly + 1) * 32 + 2 * lx + 1]) * 0.25f;
        B[tid] = r;
        *reinterpret_cast<u32x2*>(L3 + ((size_t)(ty * 16 + ly) * 64 + tx * 16 + lx) * 16 + q * 4) = pack4(r);
    }
    __syncthreads();

    if (tid < 64) {   // L4: 8x8
        int ly = tid >> 3, lx = tid & 7;
        f4v r = (B[(2 * ly) * 16 + 2 * lx]     + B[(2 * ly) * 16 + 2 * lx + 1] +
                 B[(2 * ly + 1) * 16 + 2 * lx] + B[(2 * ly + 1) * 16 + 2 * lx + 1]) * 0.25f;
        A[tid] = r;
        *reinterpret_cast<u32x2*>(L4 + ((size_t)(ty * 8 + ly) * 32 + tx * 8 + lx) * 16 + q * 4) = pack4(r);
    }
    __syncthreads();

    if (tid < 16) {   // L5: 4x4
        int ly = tid >> 2, lx = tid & 3;
        f4v r = (A[(2 * ly) * 8 + 2 * lx]     + A[(2 * ly) * 8 + 2 * lx + 1] +
                 A[(2 * ly + 1) * 8 + 2 * lx] + A[(2 * ly + 1) * 8 + 2 * lx + 1]) * 0.25f;
        B[tid] = r;
        *reinterpret_cast<u32x2*>(L5 + ((size_t)(ty * 4 + ly) * 16 + tx * 4 + lx) * 16 + q * 4) = pack4(r);
    }
    __syncthreads();

    if (tid < 4) {    // L6: 2x2
        int ly = tid >> 1, lx = tid & 1;
        f4v r = (B[(2 * ly) * 4 + 2 * lx]     + B[(2 * ly) * 4 + 2 * lx + 1] +
                 B[(2 * ly + 1) * 4 + 2 * lx] + B[(2 * ly + 1) * 4 + 2 * lx + 1]) * 0.25f;
        A[tid] = r;
        *reinterpret_cast<u32x2*>(L6 + ((size_t)(ty * 2 + ly) * 8 + tx * 2 + lx) * 16 + q * 4) = pack4(r);
    }
    __syncthreads();

    if (tid == 0) {   // L7: 1 texel
        f4v r = (A[0] + A[1] + A[2] + A[3]) * 0.25f;
        *reinterpret_cast<u32x2*>(L7 + ((size_t)ty * 4 + tx) * 16 + q * 4) = pack4(r);
    }
}

// Weighted 8-channel bilinear tap; levels >= 5 read from LDS copy.
__device__ __forceinline__ void bilerp8(
    const __half* __restrict__ wsh, const __half* __restrict__ lds_h,
    int p, int l, float u, float v, int h, float* o)
{
    const int sz = 512 >> l;
    const float fsz = (float)sz;
    float px = u * fsz - 0.5f;
    float py = v * fsz - 0.5f;
    float xf = floorf(px), yf = floorf(py);
    float fx = px - xf, fy = py - yf;
    int xi = (int)xf, yi = (int)yf;
    int xa = min(max(xi, 0), sz - 1);
    int xb = min(xi + 1, sz - 1);      // xi >= -1 always
    int ya = min(max(yi, 0), sz - 1);
    int yb = min(yi + 1, sz - 1);
    f4v q00, q01, q10, q11;
    if (l >= 5) {
        const int sel = (l == 6) ? 256 : ((l == 7) ? 320 : 0);
        const __half* base = lds_h + (size_t)(p * 336 + sel) * 16 + h * 8;
        const __half* r0 = base + (ya * sz) * 16;
        const __half* r1 = base + (yb * sz) * 16;
        q00 = ldraw_h(r0 + xa * 16);
        q01 = ldraw_h(r0 + xb * 16);
        q10 = ldraw_h(r1 + xa * 16);
        q11 = ldraw_h(r1 + xb * 16);
    } else {
        const __half* base = wsh + (size_t)p * PSTRIDE_H + (size_t)lvl_off(l) * 16 + h * 8;
        const __half* r0 = base + (size_t)(ya * sz) * 16;
        const __half* r1 = base + (size_t)(yb * sz) * 16;
        q00 = ldraw_h(r0 + (size_t)xa * 16);
        q01 = ldraw_h(r0 + (size_t)xb * 16);
        q10 = ldraw_h(r1 + (size_t)xa * 16);
        q11 = ldraw_h(r1 + (size_t)xb * 16);
    }
    float gx = 1.f - fx, gy = 1.f - fy;
    float w00 = gx * gy, w01 = fx * gy, w10 = gx * fy, w11 = fx * fy;
    #pragma unroll
    for (int i = 0; i < 4; ++i) {
        float2 a = up2(q00[i]), b = up2(q01[i]), c = up2(q10[i]), d = up2(q11[i]);
        o[2 * i]     = a.x * w00 + b.x * w01 + c.x * w10 + d.x * w11;
        o[2 * i + 1] = a.y * w00 + b.y * w01 + c.y * w10 + d.y * w11;
    }
}

// One thread per (point n, plane p, half h): t = (n*3 + p)*2 + h.
// Block 512; LDS holds levels 5..7 of all 3 planes (31.5 KB).
__global__ __launch_bounds__(512) void trimip_sample_h(
    const float* __restrict__ xyz, const float* __restrict__ level,
    const __half* __restrict__ wsh, float* __restrict__ out, int N)
{
    __shared__ u32x4 lds[2016];       // 3 planes * 336 texels * 32 B = 32256 B
    for (int uidx = threadIdx.x; uidx < 2016; uidx += 512) {
        int p = uidx / 672;           // 672 16-B units per plane
        int rem = uidx - p * 672;
        lds[uidx] = *reinterpret_cast<const u32x4*>(
            wsh + (size_t)p * PSTRIDE_H + (size_t)LVL5_OFF * 16 + (size_t)rem * 8);
    }
    __syncthreads();
    const __half* lds_h = reinterpret_cast<const __half*>(lds);

    int t = blockIdx.x * 512 + threadIdx.x;
    if (t >= N * 6) return;
    const int h = t & 1;
    const int r = t >> 1;
    const int n = r / 3;
    const int p = r - n * 3;

    const float c0 = xyz[n * 3 + 0];
    const float c1 = xyz[n * 3 + 1];
    const float c2 = xyz[n * 3 + 2];
    const float u = (p == 0) ? c1 : c0;
    const float v = (p == 2) ? c1 : c2;

    float lv = level[n];
    lv = fminf(fmaxf(lv, 0.f), 7.f);
    float lf = floorf(lv);
    float f = lv - lf;
    int l0 = (int)lf;
    int l1 = min(l0 + 1, 7);

    float s0[8], s1[8];
    bilerp8(wsh, lds_h, p, l0, u, v, h, s0);
    bilerp8(wsh, lds_h, p, l1, u, v, h, s1);
    float g = 1.f - f;
    f4v oa, ob;
    #pragma unroll
    for (int i = 0; i < 4; ++i) {
        oa[i] = s0[i] * g + s1[i] * f;
        ob[i] = s0[4 + i] * g + s1[4 + i] * f;
    }
    st4nt(out + (size_t)t * 8, oa);
    st4nt(out + (size_t)t * 8 + 4, ob);
}

// ---------------- fp32 fallback path ----------------

__device__ __forceinline__ f4v avg4(f4v a, f4v b, f4v c, f4v d) {
    return (a + b + c + d) * 0.25f;
}

__global__ __launch_bounds__(256) void mip_build_f(
    const float* __restrict__ src, float* __restrict__ dst)
{
    int t = blockIdx.x * blockDim.x + threadIdx.x;
    const int p = blockIdx.y;
    const int q = t & 3, idx = t >> 2;
    const int y = idx >> 8, x = idx & 255;
    const float* sp = src + (size_t)p * FM_PLANE_STRIDE
                          + ((size_t)(2 * y) * 512 + 2 * x) * 16 + q * 4;
    f4v r = avg4(ld4(sp), ld4(sp + 16), ld4(sp + 512 * 16), ld4(sp + 512 * 16 + 16));
    st4(dst + (size_t)p * WS_PLANE_STRIDE + ((size_t)y * 256 + x) * 16 + q * 4, r);
}

__global__ __launch_bounds__(256) void mip_tail_f(float* __restrict__ mips)
{
    const int tile = blockIdx.x, q = blockIdx.y, p = blockIdx.z;
    const int ty = tile >> 2, tx = tile & 3;
    const int tid = threadIdx.x;
    __shared__ f4v A[32 * 32];
    __shared__ f4v B[16 * 16];
    float* plane = mips + (size_t)p * WS_PLANE_STRIDE;
    const float* L1 = plane;
    float* L2 = plane + (size_t)65536 * 16;
    float* L3 = plane + (size_t)81920 * 16;
    float* L4 = plane + (size_t)86016 * 16;
    float* L5 = plane + (size_t)87040 * 16;
    float* L6 = plane + (size_t)87296 * 16;
    float* L7 = plane + (size_t)87360 * 16;

    #pragma unroll
    for (int k = 0; k < 4; ++k) {
        int li = tid + k * 256;
        int ly = li >> 5, lx = li & 31;
        int gy = ty * 32 + ly, gx = tx * 32 + lx;
        const float* sp = L1 + ((size_t)(2 * gy) * 256 + 2 * gx) * 16 + q * 4;
        f4v r = avg4(ld4(sp), ld4(sp + 16), ld4(sp + 256 * 16), ld4(sp + 256 * 16 + 16));
        A[li] = r;
        st4(L2 + ((size_t)gy * 128 + gx) * 16 + q * 4, r);
    }
    __syncthreads();
    {
        int ly = tid >> 4, lx = tid & 15;
        f4v r = avg4(A[(2 * ly) * 32 + 2 * lx],     A[(2 * ly) * 32 + 2 * lx + 1],
                     A[(2 * ly + 1) * 32 + 2 * lx], A[(2 * ly + 1) * 32 + 2 * lx + 1]);
        B[tid] = r;
        st4(L3 + ((size_t)(ty * 16 + ly) * 64 + tx * 16 + lx) * 16 + q * 4, r);
    }
    __syncthreads();
    if (tid < 64) {
        int ly = tid >> 3, lx = tid & 7;
        f4v r = avg4(B[(2 * ly) * 16 + 2 * lx],     B[(2 * ly) * 16 + 2 * lx + 1],
                     B[(2 * ly + 1) * 16 + 2 * lx], B[(2 * ly + 1) * 16 + 2 * lx + 1]);
        A[tid] = r;
        st4(L4 + ((size_t)(ty * 8 + ly) * 32 + tx * 8 + lx) * 16 + q * 4, r);
    }
    __syncthreads();
    if (tid < 16) {
        int ly = tid >> 2, lx = tid & 3;
        f4v r = avg4(A[(2 * ly) * 8 + 2 * lx],     A[(2 * ly) * 8 + 2 * lx + 1],
                     A[(2 * ly + 1) * 8 + 2 * lx], A[(2 * ly + 1) * 8 + 2 * lx + 1]);
        B[tid] = r;
        st4(L5 + ((size_t)(ty * 4 + ly) * 16 + tx * 4 + lx) * 16 + q * 4, r);
    }
    __syncthreads();
    if (tid < 4) {
        int ly = tid >> 1, lx = tid & 1;
        f4v r = avg4(B[(2 * ly) * 4 + 2 * lx],     B[(2 * ly) * 4 + 2 * lx + 1],
                     B[(2 * ly + 1) * 4 + 2 * lx], B[(2 * ly + 1) * 4 + 2 * lx + 1]);
        A[tid] = r;
        st4(L6 + ((size_t)(ty * 2 + ly) * 8 + tx * 2 + lx) * 16 + q * 4, r);
    }
    __syncthreads();
    if (tid == 0) {
        f4v r = avg4(A[0], A[1], A[2], A[3]);
        st4(L7 + ((size_t)ty * 4 + tx) * 16 + q * 4, r);
    }
}

__device__ __forceinline__ f4v bilerp_f(
    const float* __restrict__ fm, const float* __restrict__ mips,
    int p, int l, float u, float v, int q)
{
    const int sz = 512 >> l;
    const float fsz = (float)sz;
    float px = u * fsz - 0.5f;
    float py = v * fsz - 0.5f;
    float xf = floorf(px), yf = floorf(py);
    float fx = px - xf, fy = py - yf;
    int xi = (int)xf, yi = (int)yf;
    int xa = min(max(xi, 0), sz - 1);
    int xb = min(xi + 1, sz - 1);
    int ya = min(max(yi, 0), sz - 1);
    int yb = min(yi + 1, sz - 1);
    const float* base;
    if (l == 0) {
        base = fm + (size_t)p * FM_PLANE_STRIDE;
    } else {
        unsigned off = (262144u - ((unsigned)(sz * sz) << 2)) / 3u;
        base = mips + (size_t)p * WS_PLANE_STRIDE + (size_t)off * 16;
    }
    const float* r0 = base + (size_t)(ya * sz) * 16 + q * 4;
    const float* r1 = base + (size_t)(yb * sz) * 16 + q * 4;
    f4v f00 = ld4(r0 + xa * 16);
    f4v f01 = ld4(r0 + xb * 16);
    f4v f10 = ld4(r1 + xa * 16);
    f4v f11 = ld4(r1 + xb * 16);
    float gx = 1.f - fx, gy = 1.f - fy;
    return (f00 * gx + f01 * fx) * gy + (f10 * gx + f11 * fx) * fy;
}

__global__ __launch_bounds__(256) void trimip_sample_f(
    const float* __restrict__ xyz, const float* __restrict__ level,
    const float* __restrict__ fm, const float* __restrict__ mips,
    float* __restrict__ out, int N)
{
    int t = blockIdx.x * blockDim.x + threadIdx.x;
    if (t >= N * 12) return;
    const int q = t & 3;
    const int r = t >> 2;
    const int n = r / 3;
    const int p = r - n * 3;
    const float c0 = xyz[n * 3 + 0];
    const float c1 = xyz[n * 3 + 1];
    const float c2 = xyz[n * 3 + 2];
    const float u = (p == 0) ? c1 : c0;
    const float v = (p == 2) ? c1 : c2;
    float lv = level[n];
    lv = fminf(fmaxf(lv, 0.f), 7.f);
    float lf = floorf(lv);
    float f = lv - lf;
    int l0 = (int)lf;
    int l1 = min(l0 + 1, 7);
    f4v s0 = bilerp_f(fm, mips, p, l0, u, v, q);
    f4v s1 = bilerp_f(fm, mips, p, l1, u, v, q);
    f4v o = s0 * (1.f - f) + s1 * f;
    st4nt(out + (size_t)t * 4, o);
}

extern "C" void kernel_launch(void* const* d_in, const int* in_sizes, int n_in,
                              void* d_out, int out_size, void* d_ws, size_t ws_size,
                              hipStream_t stream) {
    const float* xyz   = (const float*)d_in[0];
    const float* level = (const float*)d_in[1];
    const float* fm    = (const float*)d_in[2];
    float* out = (float*)d_out;
    const int N = in_sizes[1];

    if (ws_size >= WS_H_BYTES) {
        __half* wsh = (__half*)d_ws;
        mip_convert_l1<<<dim3(1024, 3), dim3(256), 0, stream>>>(fm, wsh);
        mip_tail_h<<<dim3(16, 4, 3), dim3(256), 0, stream>>>(wsh);
        const int total = N * 6;
        trimip_sample_h<<<(total + 511) / 512, 512, 0, stream>>>(xyz, level, wsh, out, N);
    } else {
        float* mips = (float*)d_ws;
        mip_build_f<<<dim3(1024, 3), dim3(256), 0, stream>>>(fm, mips);
        mip_tail_f<<<dim3(16, 4, 3), dim3(256), 0, stream>>>(mips);
        const int total = N * 12;
        trimip_sample_f<<<(total + 255) / 256, 256, 0, stream>>>(xyz, level, fm, mips, out, N);
    }
}